// Round 1
// baseline (16964.886 us; speedup 1.0000x reference)
//
#include <hip/hip_runtime.h>
#include <stdint.h>

#define B_  16
#define T_  2048
#define D_  512

typedef short v8s __attribute__((ext_vector_type(8)));
typedef float v4f __attribute__((ext_vector_type(4)));

// ws layout (bytes)
#define WT_OFF    0u           // 8 MB  bf16 weight fragments (2 layer x 2 mat x 512 x 2048)
#define H0_OFF    8388608u     // 32 MB h0[t][b][d] bf16
#define H1_OFF    41943040u    // 32 MB h1[t][b][d] bf16
#define FLAGS_OFF 75497472u    // 128 ints (flags0[64], flags1[64]), padded to 4KB
#define XB_OFF    75501568u    // 32 MB x_bf16[t][b][d] (optional)
#define WS_NEED_FULL (XB_OFF + 33554432u)

__device__ __forceinline__ short f2bf(float f) {
  unsigned u = __builtin_bit_cast(unsigned, f);
  u = (u + 0x7FFFu + ((u >> 16) & 1u)) >> 16;
  return (short)u;
}

__device__ __forceinline__ float sigmoid_fast(float z) {
  return 1.f / (1.f + __expf(-z));
}
__device__ __forceinline__ float tanh_fast(float z) {
  float e = __expf(2.f * z);
  return 1.f - 2.f / (e + 1.f);
}

// Transpose Wx/Wh (fp32 [L][512][2048]) into bf16 MFMA B-fragment layout:
// wT[(((l*2+mat)*64+g)*2+ntile)*16+kap][lane][j]  with
//   lane = quad*16+n,  B[k=kap*32+quad*8+j][col= 512*q + g*8 + jj], c=q*8+jj=ntile*16+n
__global__ void prep_weights(const float* __restrict__ Wx, const float* __restrict__ Wh,
                             short* __restrict__ wT, int* __restrict__ flags) {
  int tid = blockIdx.x * 256 + threadIdx.x;            // [0, 2^22)
  if (blockIdx.x == 0 && threadIdx.x < 128) flags[threadIdx.x] = 0;
  int l   = tid >> 21;
  int mat = (tid >> 20) & 1;
  int rem = tid & ((1 << 20) - 1);
  int k   = rem >> 11;
  int col = rem & 2047;
  const float* src = mat ? Wh : Wx;
  float v = src[(l << 20) + (k << 11) + col];
  int q = col >> 9, r9 = col & 511, g = r9 >> 3, jj = r9 & 7;
  int c = q * 8 + jj, ntile = c >> 4, n = c & 15;
  int kap = k >> 5, k5 = k & 31, quad = k5 >> 3, j = k5 & 7;
  int lane = quad * 16 + n;
  int dst = ((((l * 2 + mat) * 64 + g) * 2 + ntile) * 16 + kap) * 512 + lane * 8 + j;
  wT[dst] = f2bf(v);
}

// x [b][t][d] fp32  ->  xb [t][b][d] bf16
__global__ void prep_x(const float* __restrict__ x, short* __restrict__ xb) {
  int tid = blockIdx.x * 256 + threadIdx.x;            // [0, 2^24)
  int b = tid >> 20, r = tid & ((1 << 20) - 1), t = r >> 9, d = r & 511;
  xb[((t * 16 + b) << 9) + d] = f2bf(x[tid]);
}

template <bool XBF16>
__global__ __launch_bounds__(256, 1) void lstm_persist(
    const float* __restrict__ x, const short* __restrict__ xb,
    const short* __restrict__ wT, const float* __restrict__ bias,
    short* h0, short* h1, int* flags, float* __restrict__ out) {
  const int wg   = blockIdx.x;
  const int l    = wg >> 6;       // layer 0 or 1
  const int g    = wg & 63;       // column group
  const int tid  = threadIdx.x;
  const int wave = tid >> 6;
  const int lane = tid & 63;
  const int mat  = wave >> 1;     // 0 = input kernel (Wx), 1 = recurrent (Wh)
  const int ntile = wave & 1;
  const int n15  = lane & 15;
  const int quad = lane >> 4;

  __shared__ float LDSG[2][16][33];

  int* flags0 = flags;
  int* flags1 = flags + 64;
  int* flagsOwn = l ? flags1 : flags0;
  short* hOwn = l ? h1 : h0;

  // loop-invariant B fragments -> registers (64 VGPRs)
  v8s bfrag[16];
  {
    const short* wb = wT + (size_t)((((l * 2 + mat) * 64 + g) * 2 + ntile) * 16) * 512;
#pragma unroll
    for (int kk = 0; kk < 16; ++kk)
      bfrag[kk] = *(const v8s*)(wb + kk * 512 + lane * 8);
  }

  // per-thread epilogue state (tid < 128): thread -> (batch bb, col jj)
  const int bb = tid >> 3, jj = tid & 7;
  const int colg = g * 8 + jj;                       // d index in [0,512)
  float bq[4];
#pragma unroll
  for (int q = 0; q < 4; ++q) bq[q] = bias[l * 2048 + q * 512 + colg];
  float c_state = 0.f;
  const size_t xTB = (size_t)bb * T_ * D_ + colg;    // x[bb][t][colg] base (add t*512)

  for (int t = 0; t < T_; ++t) {
    // ---------- wait for inputs ----------
    const bool needPoll = (l == 1) || (t > 0);
    if (needPoll) {
      if (wave == 0) {
        for (;;) {
          bool p;
          if (l == 0) {
            int f = __hip_atomic_load(&flags0[lane], __ATOMIC_RELAXED, __HIP_MEMORY_SCOPE_AGENT);
            p = (f >= t);
          } else {
            int fp = __hip_atomic_load(&flags0[lane], __ATOMIC_RELAXED, __HIP_MEMORY_SCOPE_AGENT);
            p = (fp >= t + 1);
            if (t > 0) {
              int fo = __hip_atomic_load(&flags1[lane], __ATOMIC_RELAXED, __HIP_MEMORY_SCOPE_AGENT);
              p = p && (fo >= t);
            }
          }
          if (__ballot(p) == 0xFFFFFFFFFFFFFFFFull) break;
          __builtin_amdgcn_s_sleep(1);
        }
        __builtin_amdgcn_fence(__ATOMIC_ACQUIRE, "agent");
      }
      __syncthreads();
    }

    // ---------- MFMA: this wave's 16-col tile of (A @ Wmat) ----------
    v4f acc = {0.f, 0.f, 0.f, 0.f};
    const bool doIt = (mat == 0) || (t > 0);
    if (doIt) {
      if (!XBF16 && mat == 0 && l == 0) {
        const float* A = x + (size_t)(n15 * T_ + t) * D_ + quad * 8;
#pragma unroll
        for (int kk = 0; kk < 16; ++kk) {
          float4 f0 = *(const float4*)(A + kk * 32);
          float4 f1 = *(const float4*)(A + kk * 32 + 4);
          v8s a;
          a[0] = f2bf(f0.x); a[1] = f2bf(f0.y); a[2] = f2bf(f0.z); a[3] = f2bf(f0.w);
          a[4] = f2bf(f1.x); a[5] = f2bf(f1.y); a[6] = f2bf(f1.z); a[7] = f2bf(f1.w);
          acc = __builtin_amdgcn_mfma_f32_16x16x32_bf16(a, bfrag[kk], acc, 0, 0, 0);
        }
      } else {
        const short* A;
        if (mat == 0) {
          A = (l == 0) ? (xb + ((size_t)(t * 16 + n15) << 9) + quad * 8)
                       : (h0 + ((size_t)(t * 16 + n15) << 9) + quad * 8);
        } else {
          A = hOwn + ((size_t)((t - 1) * 16 + n15) << 9) + quad * 8;
        }
#pragma unroll
        for (int kk = 0; kk < 16; ++kk) {
          v8s a = *(const v8s*)(A + kk * 32);
          acc = __builtin_amdgcn_mfma_f32_16x16x32_bf16(a, bfrag[kk], acc, 0, 0, 0);
        }
      }
    }
    {
      const int rb = quad * 4;
#pragma unroll
      for (int r = 0; r < 4; ++r)
        LDSG[mat][rb + r][ntile * 16 + n15] = acc[r];
    }
    __syncthreads();

    // ---------- epilogue: gates -> (c,h) ----------
    if (tid < 128) {
      float pa[4];
#pragma unroll
      for (int q = 0; q < 4; ++q)
        pa[q] = LDSG[0][bb][q * 8 + jj] + LDSG[1][bb][q * 8 + jj] + bq[q];
      float ig = sigmoid_fast(pa[0]);
      float fg = sigmoid_fast(pa[1]);
      float gg = tanh_fast(pa[2]);
      float og = sigmoid_fast(pa[3]);
      c_state = fg * c_state + ig * gg;
      float h = og * tanh_fast(c_state);
      hOwn[((size_t)(t * 16 + bb) << 9) + colg] = f2bf(h);
      if (l == 1) {
        size_t xi = xTB + (size_t)t * D_;
        out[xi] = h + x[xi];
      }
    }
    __syncthreads();
    if (tid == 0) {
      __builtin_amdgcn_fence(__ATOMIC_RELEASE, "agent");
      __hip_atomic_store(&flagsOwn[g], t + 1, __ATOMIC_RELAXED, __HIP_MEMORY_SCOPE_AGENT);
    }
  }
}

extern "C" void kernel_launch(void* const* d_in, const int* in_sizes, int n_in,
                              void* d_out, int out_size, void* d_ws, size_t ws_size,
                              hipStream_t stream) {
  const float* x    = (const float*)d_in[0];
  const float* Wx   = (const float*)d_in[1];
  const float* Wh   = (const float*)d_in[2];
  const float* bias = (const float*)d_in[3];
  float* out = (float*)d_out;

  char* ws   = (char*)d_ws;
  short* wT  = (short*)(ws + WT_OFF);
  short* h0  = (short*)(ws + H0_OFF);
  short* h1  = (short*)(ws + H1_OFF);
  int* flags = (int*)(ws + FLAGS_OFF);
  short* xb  = (short*)(ws + XB_OFF);

  const bool xbf16 = (ws_size >= (size_t)WS_NEED_FULL);

  hipLaunchKernelGGL(prep_weights, dim3(16384), dim3(256), 0, stream, Wx, Wh, wT, flags);
  if (xbf16) {
    hipLaunchKernelGGL(prep_x, dim3(65536), dim3(256), 0, stream, x, xb);
    hipLaunchKernelGGL((lstm_persist<true>), dim3(128), dim3(256), 0, stream,
                       x, xb, wT, bias, h0, h1, flags, out);
  } else {
    hipLaunchKernelGGL((lstm_persist<false>), dim3(128), dim3(256), 0, stream,
                       x, xb, wT, bias, h0, h1, flags, out);
  }
}